// Round 4
// baseline (394.410 us; speedup 1.0000x reference)
//
#include <hip/hip_runtime.h>
#include <cstddef>

#define BB   128
#define TT   64
#define CC   6625
#define LL   25
#define KK   6
#define LSS  25
#define SS   51            // 2*LL + 1
#define NEG  (-1e30f)
#define FNEG (-3.4e38f)
#define PIVOT 16.0f

#define NCTC       (BB + BB * KK)   // 896 targets
#define CTC_BLOCKS (NCTC / 4)       // 224 blocks of 4 waves

__device__ __forceinline__ float lae(float a, float b) {
    float m = fmaxf(a, b);
    float n = fminf(a, b);
    return m + __logf(1.0f + __expf(n - m));   // fast logaddexp; NEG/NEG absorbed
}

// ---------------------------------------------------------------------------
// Kernel 1 (v4): one wave per row, ROLLING 6-DEEP PREFETCH PIPELINE.
// 2048 blocks x 4 waves = 8192 rows, 8 blocks/CU single pass.
// Each wave: 25 full 64-lane float4 chunks consumed one per iteration while
// the load 6 iterations ahead is issued -> ~6 KB permanently in flight/wave.
// Head/remainder/tail loads hoisted to the top. Branchless top-2. No LDS.
// ---------------------------------------------------------------------------
__global__ __launch_bounds__(256, 8) void row_stats_k(
    const float* __restrict__ preds,
    float* __restrict__ lse_t, float* __restrict__ t1v, float* __restrict__ t2v,
    int* __restrict__ t1i, int* __restrict__ t2i, float* __restrict__ cal)
{
    if (blockIdx.x == 0 && threadIdx.x < BB) cal[threadIdx.x] = 0.0f;

    int wave = threadIdx.x >> 6, lane = threadIdx.x & 63;
    int r = blockIdx.x * 4 + wave;           // row = b*TT + t
    const float* row = preds + (size_t)r * CC;

    int h = (4 - (r & 3)) & 3;               // scalar head to reach 16B alignment
    const float4* vp = (const float4*)(row + h);
    int nv = (CC - h) >> 2;                  // 1655 or 1656 float4s
    int t0 = h + (nv << 2);                  // scalar tail start

    // hoisted boundary loads (issued before the pipeline starts)
    float headx = (lane < h) ? row[lane] : FNEG;
    float tailx = (lane < CC - t0) ? row[t0 + lane] : FNEG;
    int   remidx = 1600 + lane;
    bool  remv = remidx < nv;
    float4 remx = vp[remv ? remidx : 0];

    float s0 = 0.0f, s1 = 0.0f, s2 = 0.0f, s3 = 0.0f;
    float v1 = FNEG, v2 = FNEG;
    int   i1 = 0x7fffffff, i2 = 0x7fffffff;

    auto top2 = [&](float x, int c) {        // branchless: 2 cmp + 4 cndmask
        bool g1 = (x > v1);
        bool g2 = (x > v2);
        v2 = g1 ? v1 : (g2 ? x : v2);
        i2 = g1 ? i1 : (g2 ? c : i2);
        v1 = g1 ? x : v1;
        i1 = g1 ? c : i1;
    };
    auto proc4 = [&](float4 x, int c) {
        s0 += __expf(x.x - PIVOT);
        s1 += __expf(x.y - PIVOT);
        s2 += __expf(x.z - PIVOT);
        s3 += __expf(x.w - PIVOT);
        top2((c == 0) ? FNEG : x.x, c);      // blank col 0 excluded from top2
        top2(x.y, c + 1);
        top2(x.z, c + 2);
        top2(x.w, c + 3);
    };

    // rolling pipeline over 25 full chunks, 6 loads always in flight
    float4 buf[6];
    #pragma unroll
    for (int k = 0; k < 6; ++k) buf[k] = vp[k * 64 + lane];
    #pragma unroll
    for (int k = 0; k < 25; ++k) {
        float4 x = buf[k % 6];
        if (k + 6 < 25) buf[k % 6] = vp[(k + 6) * 64 + lane];
        proc4(x, h + (k * 64 + lane) * 4);
    }

    // boundaries
    if (lane < h) {                          // head cols 0..h-1
        s0 += __expf(headx - PIVOT);
        if (lane > 0) top2(headx, lane);     // col 0 (blank) excluded
    }
    if (remv) proc4(remx, h + (remidx << 2));
    if (lane < CC - t0) {
        s0 += __expf(tailx - PIVOT);
        top2(tailx, t0 + lane);
    }

    float s = (s0 + s1) + (s2 + s3);
    for (int off = 32; off > 0; off >>= 1) {
        s += __shfl_xor(s, off);
        float w1 = __shfl_xor(v1, off); int j1 = __shfl_xor(i1, off);
        float w2 = __shfl_xor(v2, off); int j2 = __shfl_xor(i2, off);
        bool b1 = (w1 > v1) || (w1 == v1 && j1 < i1);
        bool b2a = (v1 > w2) || (v1 == w2 && i1 < j2);
        bool b2b = (w1 > v2) || (w1 == v2 && j1 < i2);
        float nv2 = b1 ? (b2a ? v1 : w2) : (b2b ? w1 : v2);
        int   ni2 = b1 ? (b2a ? i1 : j2) : (b2b ? j1 : i2);
        v1 = b1 ? w1 : v1; i1 = b1 ? j1 : i1;
        v2 = nv2; i2 = ni2;
    }

    if (lane == 0) {
        int b = r >> 6, t = r & 63;          // TT = 64
        int tr = t * BB + b;                 // [T][B] transposed
        lse_t[tr] = PIVOT + __logf(s);
        t1v[tr] = v1; t1i[tr] = i1;
        t2v[tr] = v2; t2i[tr] = i2;
    }
}

// ---------------------------------------------------------------------------
// Kernel 2: merged CTC + beam. Both run SHIFT-INVARIANT (raw preds, no
// per-frame lse subtraction); a single sum(lse) correction is applied at the
// end — every trellis/beam path accumulates exactly one emission per frame.
// ---------------------------------------------------------------------------
__global__ __launch_bounds__(256) void ctc_beam_k(
    const float* __restrict__ preds, const float* __restrict__ lse_t,
    const float* __restrict__ t1v, const float* __restrict__ t2v,
    const int* __restrict__ t1i, const int* __restrict__ t2i,
    const int* __restrict__ text, const int* __restrict__ length,
    const int* __restrict__ preds_size,
    const int* __restrict__ smooth_text, const int* __restrict__ smooth_length,
    float* __restrict__ nllm, float* __restrict__ cal, float* __restrict__ ranking)
{
    if (blockIdx.x == CTC_BLOCKS) {
        // ---------------- beam search (confidence), one thread per sample ----
        int b = threadIdx.x;
        if (b >= BB) return;
        const float* pb = preds + (size_t)b * TT * CC;

        float sum_lse = 0.0f;                      // not in the dependent chain
        #pragma unroll 8
        for (int t = 0; t < TT; ++t) sum_lse += lse_t[t * BB + b];

        float lpb = 0.0f, lpnb = NEG;
        int last = -1;
        float pf0[8];
        #pragma unroll
        for (int i = 0; i < 8; ++i) pf0[i] = pb[(size_t)i * CC];   // blank column
        float lplast_raw = 0.0f;
        for (int t = 0; t < TT; ++t) {
            int tr = t * BB + b;
            float w1 = t1v[tr]; int j1 = t1i[tr];
            float w2 = t2v[tr]; int j2 = t2i[tr];
            float lp0 = pf0[t & 7];
            if (t + 8 < TT) pf0[t & 7] = pb[(size_t)(t + 8) * CC];
            float tot = lae(lpb, lpnb);
            float new_pb = tot + lp0;
            float rep = (last >= 0) ? (lpnb + lplast_raw) : NEG;
            float keep = lae(new_pb, rep);
            float best_ext; int best_c;
            if (j1 == last) {
                float eA = lpb + w1;               // ext[last] uses lpb base
                float eB = tot + w2;               // runner-up with tot base
                if (eA > eB || (eA == eB && last < j2)) { best_ext = eA; best_c = last; }
                else                                    { best_ext = eB; best_c = j2; }
            } else {
                best_ext = tot + w1;               // tot>=lpb and w1>=raw[last]
                best_c = j1;
            }
            bool take = best_ext > keep;
            lpb  = take ? NEG : new_pb;
            lpnb = take ? best_ext : rep;
            last = take ? best_c : last;
            if (t + 1 < TT && last >= 0) lplast_raw = pb[(size_t)(t + 1) * CC + last];
        }
        float score = lae(lpb, lpnb) - sum_lse;
        float conf = __expf(score * (1.0f / TT));
        float om = 1.0f - conf;
        ranking[b] = 0.01f + 0.99f * om * om;   // SMOOTH_TAIL + (1-SMOOTH_TAIL)(1-conf)^2
        return;
    }

    // ---------------- CTC alpha recursion: one wave per target ---------------
    int wave = threadIdx.x >> 6, lane = threadIdx.x & 63;
    int n = blockIdx.x * 4 + wave;
    if (n >= NCTC) return;
    bool master = n < BB;
    int b, tlen, input_len;
    const int* tgt;
    if (master) {
        b = n; tgt = text + (size_t)n * LL; tlen = length[n]; input_len = preds_size[b];
    } else {
        int ns = n - BB;
        b = ns / KK; tgt = smooth_text + (size_t)ns * LSS; tlen = smooth_length[ns]; input_len = TT;
    }

    // extended label per lane (state s = lane): even -> blank(0), odd -> tgt[(s-1)/2]
    int s = lane;
    int ext = 0; bool skipok = false;
    if (s < SS && (s & 1)) {
        int li = (s - 1) >> 1;
        ext = tgt[li];
        skipok = (ext != 0) && (li == 0 || ext != tgt[li - 1]);
    }

    const float* pb = preds + (size_t)b * TT * CC;

    // sum of lse over t < input_len (lane = t), wave-reduced once
    float sum_lse = (lane < input_len) ? lse_t[lane * BB + b] : 0.0f;
    for (int off = 32; off > 0; off >>= 1) sum_lse += __shfl_xor(sum_lse, off);

    float alpha = NEG;
    if (s < 2) alpha = pb[ext];              // raw init (t=0)

    // 8-deep gather prefetch: addresses lane-constant (ext fixed per lane)
    float pf[8];
    #pragma unroll
    for (int i = 0; i < 8; ++i) pf[i] = pb[(size_t)(1 + i) * CC + ext];
    for (int t = 1; t < TT; ++t) {
        int slot = (t - 1) & 7;
        float lp = pf[slot];                 // raw emission
        if (t + 8 < TT) pf[slot] = pb[(size_t)(t + 8) * CC + ext];
        float a0 = alpha;
        float a1 = __shfl_up(alpha, 1); a1 = (lane >= 1) ? a1 : NEG;
        float a2 = __shfl_up(alpha, 2); a2 = (lane >= 2 && skipok) ? a2 : NEG;
        float m = fmaxf(a0, fmaxf(a1, a2));
        float tot = m + __logf(__expf(a0 - m) + __expf(a1 - m) + __expf(a2 - m));
        float anew = tot + lp;
        alpha = (t < input_len) ? anew : alpha;
    }

    int il = 2 * tlen;                        // <= 50 < SS
    float a_bl = __shfl(alpha, il);
    float a_ch = __shfl(alpha, il > 0 ? il - 1 : 0);
    float nll = sum_lse - lae(a_bl, a_ch);    // normalization applied once
    if (nll > 1e29f) nll = 0.0f;              // zero_infinity
    if (lane == 0) {
        float v = nll / (float)tlen;
        if (master) nllm[b] = v;
        else        atomicAdd(&cal[b], v * (1.0f / KK));
    }
}

// ---------------------------------------------------------------------------
// Kernel 3: final scalar: mean_b( nllm[b] + ALPHA * ranking[b] * cal[b] )
// ---------------------------------------------------------------------------
__global__ __launch_bounds__(128) void final_k(
    const float* __restrict__ nllm, const float* __restrict__ ranking,
    const float* __restrict__ cal, float* __restrict__ out)
{
    int b = threadIdx.x;
    float v = nllm[b] + 0.1f * ranking[b] * cal[b];
    for (int off = 32; off > 0; off >>= 1) v += __shfl_xor(v, off);
    __shared__ float sv[2];
    if ((b & 63) == 0) sv[b >> 6] = v;
    __syncthreads();
    if (b == 0) out[0] = (sv[0] + sv[1]) * (1.0f / BB);
}

extern "C" void kernel_launch(void* const* d_in, const int* in_sizes, int n_in,
                              void* d_out, int out_size, void* d_ws, size_t ws_size,
                              hipStream_t stream)
{
    const float* preds         = (const float*)d_in[0];
    const int*   text          = (const int*)d_in[1];
    const int*   preds_size    = (const int*)d_in[2];
    const int*   length        = (const int*)d_in[3];
    const int*   smooth_text   = (const int*)d_in[4];
    const int*   smooth_length = (const int*)d_in[5];
    float* out = (float*)d_out;

    // workspace layout (floats): lse_t | t1v | t2v | t1i | t2i | ranking | nllm | cal
    const int RT = BB * TT;  // 8192 rows
    float* ws     = (float*)d_ws;
    float* lse_t  = ws;
    float* t1v    = ws + RT;
    float* t2v    = ws + 2 * RT;
    int*   t1i    = (int*)(ws + 3 * RT);
    int*   t2i    = (int*)(ws + 4 * RT);
    float* ranking = ws + 5 * RT;
    float* nllm    = ranking + BB;
    float* cal     = nllm + BB;

    row_stats_k<<<RT / 4, 256, 0, stream>>>(preds, lse_t, t1v, t2v, t1i, t2i, cal);
    ctc_beam_k<<<CTC_BLOCKS + 1, 256, 0, stream>>>(preds, lse_t, t1v, t2v, t1i, t2i,
                                                   text, length, preds_size,
                                                   smooth_text, smooth_length,
                                                   nllm, cal, ranking);
    final_k<<<1, 128, 0, stream>>>(nllm, ranking, cal, out);
}

// Round 5
// 347.738 us; speedup vs baseline: 1.1342x; 1.1342x over previous
//
#include <hip/hip_runtime.h>
#include <cstddef>

#define BB   128
#define TT   64
#define CC   6625
#define LL   25
#define KK   6
#define LSS  25
#define SS   51            // 2*LL + 1
#define NEG  (-1e30f)
#define FNEG (-3.4e38f)
#define PIVOT 16.0f

#define NCTC       (BB + BB * KK)   // 896 targets
#define CTC_BLOCKS (NCTC / 4)       // 224 blocks of 4 waves

__device__ __forceinline__ float lae(float a, float b) {
    float m = fmaxf(a, b);
    float n = fminf(a, b);
    return m + __logf(1.0f + __expf(n - m));   // fast logaddexp; NEG/NEG absorbed
}

// ---------------------------------------------------------------------------
// Kernel 1 (v5): one wave per row, rolling 6-deep prefetch ring.
// __launch_bounds__(256, 4): 128-VGPR budget so the ring + hoisted boundary
// loads actually live in registers (v4's (256,8)=64-reg cap spilled; R2's
// profile showed the allocator squeezing us to 12 VGPRs = no MLP at all).
// 16 waves/CU x 6 KB in flight/wave = 96 KB/CU outstanding.
// ---------------------------------------------------------------------------
__global__ __launch_bounds__(256, 4) void row_stats_k(
    const float* __restrict__ preds,
    float* __restrict__ lse_t, float* __restrict__ t1v, float* __restrict__ t2v,
    int* __restrict__ t1i, int* __restrict__ t2i, float* __restrict__ cal)
{
    if (blockIdx.x == 0 && threadIdx.x < BB) cal[threadIdx.x] = 0.0f;

    int wave = threadIdx.x >> 6, lane = threadIdx.x & 63;
    int r = blockIdx.x * 4 + wave;           // row = b*TT + t
    const float* row = preds + (size_t)r * CC;

    int h = (4 - (r & 3)) & 3;               // scalar head to reach 16B alignment
    const float4* vp = (const float4*)(row + h);
    int nv = (CC - h) >> 2;                  // 1655 or 1656 float4s
    int t0 = h + (nv << 2);                  // scalar tail start

    // hoisted boundary loads (issued before the pipeline starts)
    float headx = (lane < h) ? row[lane] : FNEG;
    float tailx = (lane < CC - t0) ? row[t0 + lane] : FNEG;
    int   remidx = 1600 + lane;
    bool  remv = remidx < nv;
    float4 remx = vp[remv ? remidx : 0];

    float s0 = 0.0f, s1 = 0.0f, s2 = 0.0f, s3 = 0.0f;
    float v1 = FNEG, v2 = FNEG;
    int   i1 = 0x7fffffff, i2 = 0x7fffffff;

    auto top2 = [&](float x, int c) {        // branchless: 2 cmp + 4 cndmask
        bool g1 = (x > v1);
        bool g2 = (x > v2);
        v2 = g1 ? v1 : (g2 ? x : v2);
        i2 = g1 ? i1 : (g2 ? c : i2);
        v1 = g1 ? x : v1;
        i1 = g1 ? c : i1;
    };
    auto proc4 = [&](float4 x, int c) {
        s0 += __expf(x.x - PIVOT);
        s1 += __expf(x.y - PIVOT);
        s2 += __expf(x.z - PIVOT);
        s3 += __expf(x.w - PIVOT);
        top2((c == 0) ? FNEG : x.x, c);      // blank col 0 excluded from top2
        top2(x.y, c + 1);
        top2(x.z, c + 2);
        top2(x.w, c + 3);
    };

    // rolling pipeline over 25 full chunks, 6 loads always in flight
    float4 buf[6];
    #pragma unroll
    for (int k = 0; k < 6; ++k) buf[k] = vp[k * 64 + lane];
    #pragma unroll
    for (int k = 0; k < 25; ++k) {
        float4 x = buf[k % 6];
        if (k + 6 < 25) buf[k % 6] = vp[(k + 6) * 64 + lane];
        proc4(x, h + (k * 64 + lane) * 4);
    }

    // boundaries
    if (lane < h) {                          // head cols 0..h-1
        s0 += __expf(headx - PIVOT);
        if (lane > 0) top2(headx, lane);     // col 0 (blank) excluded
    }
    if (remv) proc4(remx, h + (remidx << 2));
    if (lane < CC - t0) {
        s0 += __expf(tailx - PIVOT);
        top2(tailx, t0 + lane);
    }

    float s = (s0 + s1) + (s2 + s3);
    for (int off = 32; off > 0; off >>= 1) {
        s += __shfl_xor(s, off);
        float w1 = __shfl_xor(v1, off); int j1 = __shfl_xor(i1, off);
        float w2 = __shfl_xor(v2, off); int j2 = __shfl_xor(i2, off);
        bool b1 = (w1 > v1) || (w1 == v1 && j1 < i1);
        bool b2a = (v1 > w2) || (v1 == w2 && i1 < j2);
        bool b2b = (w1 > v2) || (w1 == v2 && j1 < i2);
        float nv2 = b1 ? (b2a ? v1 : w2) : (b2b ? w1 : v2);
        int   ni2 = b1 ? (b2a ? i1 : j2) : (b2b ? j1 : i2);
        v1 = b1 ? w1 : v1; i1 = b1 ? j1 : i1;
        v2 = nv2; i2 = ni2;
    }

    if (lane == 0) {
        int b = r >> 6, t = r & 63;          // TT = 64
        int tr = t * BB + b;                 // [T][B] transposed
        lse_t[tr] = PIVOT + __logf(s);
        t1v[tr] = v1; t1i[tr] = i1;
        t2v[tr] = v2; t2i[tr] = i2;
    }
}

// ---------------------------------------------------------------------------
// Kernel 2: merged CTC + beam. Both run SHIFT-INVARIANT (raw preds, no
// per-frame lse subtraction); a single sum(lse) correction is applied at the
// end — every trellis/beam path accumulates exactly one emission per frame.
// ---------------------------------------------------------------------------
__global__ __launch_bounds__(256) void ctc_beam_k(
    const float* __restrict__ preds, const float* __restrict__ lse_t,
    const float* __restrict__ t1v, const float* __restrict__ t2v,
    const int* __restrict__ t1i, const int* __restrict__ t2i,
    const int* __restrict__ text, const int* __restrict__ length,
    const int* __restrict__ preds_size,
    const int* __restrict__ smooth_text, const int* __restrict__ smooth_length,
    float* __restrict__ nllm, float* __restrict__ cal, float* __restrict__ ranking)
{
    if (blockIdx.x == CTC_BLOCKS) {
        // ---------------- beam search (confidence), one thread per sample ----
        int b = threadIdx.x;
        if (b >= BB) return;
        const float* pb = preds + (size_t)b * TT * CC;

        float sum_lse = 0.0f;                      // not in the dependent chain
        #pragma unroll 8
        for (int t = 0; t < TT; ++t) sum_lse += lse_t[t * BB + b];

        float lpb = 0.0f, lpnb = NEG;
        int last = -1;
        float pf0[8];
        #pragma unroll
        for (int i = 0; i < 8; ++i) pf0[i] = pb[(size_t)i * CC];   // blank column
        float lplast_raw = 0.0f;
        for (int t = 0; t < TT; ++t) {
            int tr = t * BB + b;
            float w1 = t1v[tr]; int j1 = t1i[tr];
            float w2 = t2v[tr]; int j2 = t2i[tr];
            float lp0 = pf0[t & 7];
            if (t + 8 < TT) pf0[t & 7] = pb[(size_t)(t + 8) * CC];
            float tot = lae(lpb, lpnb);
            float new_pb = tot + lp0;
            float rep = (last >= 0) ? (lpnb + lplast_raw) : NEG;
            float keep = lae(new_pb, rep);
            float best_ext; int best_c;
            if (j1 == last) {
                float eA = lpb + w1;               // ext[last] uses lpb base
                float eB = tot + w2;               // runner-up with tot base
                if (eA > eB || (eA == eB && last < j2)) { best_ext = eA; best_c = last; }
                else                                    { best_ext = eB; best_c = j2; }
            } else {
                best_ext = tot + w1;               // tot>=lpb and w1>=raw[last]
                best_c = j1;
            }
            bool take = best_ext > keep;
            lpb  = take ? NEG : new_pb;
            lpnb = take ? best_ext : rep;
            last = take ? best_c : last;
            if (t + 1 < TT && last >= 0) lplast_raw = pb[(size_t)(t + 1) * CC + last];
        }
        float score = lae(lpb, lpnb) - sum_lse;
        float conf = __expf(score * (1.0f / TT));
        float om = 1.0f - conf;
        ranking[b] = 0.01f + 0.99f * om * om;   // SMOOTH_TAIL + (1-SMOOTH_TAIL)(1-conf)^2
        return;
    }

    // ---------------- CTC alpha recursion: one wave per target ---------------
    int wave = threadIdx.x >> 6, lane = threadIdx.x & 63;
    int n = blockIdx.x * 4 + wave;
    if (n >= NCTC) return;
    bool master = n < BB;
    int b, tlen, input_len;
    const int* tgt;
    if (master) {
        b = n; tgt = text + (size_t)n * LL; tlen = length[n]; input_len = preds_size[b];
    } else {
        int ns = n - BB;
        b = ns / KK; tgt = smooth_text + (size_t)ns * LSS; tlen = smooth_length[ns]; input_len = TT;
    }

    // extended label per lane (state s = lane): even -> blank(0), odd -> tgt[(s-1)/2]
    int s = lane;
    int ext = 0; bool skipok = false;
    if (s < SS && (s & 1)) {
        int li = (s - 1) >> 1;
        ext = tgt[li];
        skipok = (ext != 0) && (li == 0 || ext != tgt[li - 1]);
    }

    const float* pb = preds + (size_t)b * TT * CC;

    // sum of lse over t < input_len (lane = t), wave-reduced once
    float sum_lse = (lane < input_len) ? lse_t[lane * BB + b] : 0.0f;
    for (int off = 32; off > 0; off >>= 1) sum_lse += __shfl_xor(sum_lse, off);

    float alpha = NEG;
    if (s < 2) alpha = pb[ext];              // raw init (t=0)

    // 8-deep gather prefetch: addresses lane-constant (ext fixed per lane)
    float pf[8];
    #pragma unroll
    for (int i = 0; i < 8; ++i) pf[i] = pb[(size_t)(1 + i) * CC + ext];
    for (int t = 1; t < TT; ++t) {
        int slot = (t - 1) & 7;
        float lp = pf[slot];                 // raw emission
        if (t + 8 < TT) pf[slot] = pb[(size_t)(t + 8) * CC + ext];
        float a0 = alpha;
        float a1 = __shfl_up(alpha, 1); a1 = (lane >= 1) ? a1 : NEG;
        float a2 = __shfl_up(alpha, 2); a2 = (lane >= 2 && skipok) ? a2 : NEG;
        float m = fmaxf(a0, fmaxf(a1, a2));
        float tot = m + __logf(__expf(a0 - m) + __expf(a1 - m) + __expf(a2 - m));
        float anew = tot + lp;
        alpha = (t < input_len) ? anew : alpha;
    }

    int il = 2 * tlen;                        // <= 50 < SS
    float a_bl = __shfl(alpha, il);
    float a_ch = __shfl(alpha, il > 0 ? il - 1 : 0);
    float nll = sum_lse - lae(a_bl, a_ch);    // normalization applied once
    if (nll > 1e29f) nll = 0.0f;              // zero_infinity
    if (lane == 0) {
        float v = nll / (float)tlen;
        if (master) nllm[b] = v;
        else        atomicAdd(&cal[b], v * (1.0f / KK));
    }
}

// ---------------------------------------------------------------------------
// Kernel 3: final scalar: mean_b( nllm[b] + ALPHA * ranking[b] * cal[b] )
// ---------------------------------------------------------------------------
__global__ __launch_bounds__(128) void final_k(
    const float* __restrict__ nllm, const float* __restrict__ ranking,
    const float* __restrict__ cal, float* __restrict__ out)
{
    int b = threadIdx.x;
    float v = nllm[b] + 0.1f * ranking[b] * cal[b];
    for (int off = 32; off > 0; off >>= 1) v += __shfl_xor(v, off);
    __shared__ float sv[2];
    if ((b & 63) == 0) sv[b >> 6] = v;
    __syncthreads();
    if (b == 0) out[0] = (sv[0] + sv[1]) * (1.0f / BB);
}

extern "C" void kernel_launch(void* const* d_in, const int* in_sizes, int n_in,
                              void* d_out, int out_size, void* d_ws, size_t ws_size,
                              hipStream_t stream)
{
    const float* preds         = (const float*)d_in[0];
    const int*   text          = (const int*)d_in[1];
    const int*   preds_size    = (const int*)d_in[2];
    const int*   length        = (const int*)d_in[3];
    const int*   smooth_text   = (const int*)d_in[4];
    const int*   smooth_length = (const int*)d_in[5];
    float* out = (float*)d_out;

    // workspace layout (floats): lse_t | t1v | t2v | t1i | t2i | ranking | nllm | cal
    const int RT = BB * TT;  // 8192 rows
    float* ws     = (float*)d_ws;
    float* lse_t  = ws;
    float* t1v    = ws + RT;
    float* t2v    = ws + 2 * RT;
    int*   t1i    = (int*)(ws + 3 * RT);
    int*   t2i    = (int*)(ws + 4 * RT);
    float* ranking = ws + 5 * RT;
    float* nllm    = ranking + BB;
    float* cal     = nllm + BB;

    row_stats_k<<<RT / 4, 256, 0, stream>>>(preds, lse_t, t1v, t2v, t1i, t2i, cal);
    ctc_beam_k<<<CTC_BLOCKS + 1, 256, 0, stream>>>(preds, lse_t, t1v, t2v, t1i, t2i,
                                                   text, length, preds_size,
                                                   smooth_text, smooth_length,
                                                   nllm, cal, ranking);
    final_k<<<1, 128, 0, stream>>>(nllm, ranking, cal, out);
}

// Round 6
// 346.617 us; speedup vs baseline: 1.1379x; 1.0032x over previous
//
#include <hip/hip_runtime.h>
#include <cstddef>

#define BB   128
#define TT   64
#define CC   6625
#define LL   25
#define KK   6
#define LSS  25
#define SS   51            // 2*LL + 1
#define NEG  (-1e30f)
#define FNEG (-3.4e38f)
#define PIVOT 16.0f

#define NCTC       (BB + BB * KK)   // 896 targets
#define CTC_BLOCKS (NCTC / 4)       // 224 blocks of 4 waves

__device__ __forceinline__ float lae(float a, float b) {
    float m = fmaxf(a, b);
    float n = fminf(a, b);
    return m + __logf(1.0f + __expf(n - m));   // fast logaddexp; NEG/NEG absorbed
}

// ---------------------------------------------------------------------------
// Kernel 1 (v7): ONE BLOCK PER ROW, copy-kernel-shaped loads.
// 8192 blocks x 256 threads. Each thread: 7 statically-NAMED float4 loads
// (x0..x6 — no array, no ring rotation, no modulo indexing) all issued
// before any consumption, so the compiler has no license to serialize them.
// Only x6 needs a clamp (dummy-load vp[0], contribution masked to FNEG).
// (256,4) = 128-VGPR budget; kernel needs ~60 -> no spill.
// ---------------------------------------------------------------------------
__global__ __launch_bounds__(256, 4) void row_stats_k(
    const float* __restrict__ preds,
    float* __restrict__ lse_t, float* __restrict__ t1v, float* __restrict__ t2v,
    int* __restrict__ t1i, int* __restrict__ t2i, float* __restrict__ cal)
{
    int r = blockIdx.x;                      // row = b*TT + t
    int tid = threadIdx.x;
    if (r == 0 && tid < BB) cal[tid] = 0.0f;

    const float* row = preds + (size_t)r * CC;
    int h = (4 - (r & 3)) & 3;               // scalar head to reach 16B alignment
    const float4* vp = (const float4*)(row + h);
    int nv = (CC - h) >> 2;                  // 1655 or 1656 float4s
    int t0 = h + (nv << 2);                  // scalar tail start
    int ntail = CC - t0;                     // 0..3

    // ---- issue ALL loads up front -------------------------------------------
    float headx = (tid < h)     ? row[tid]       : FNEG;   // col = tid (>=1 only used)
    float tailx = (tid < ntail) ? row[t0 + tid]  : FNEG;   // col = t0 + tid
    int li6 = tid + 1536;                    // only the 7th load can run off the end
    bool v6ok = li6 < nv;
    float4 x0 = vp[tid];                     // tid+0*256  max 255  < 1655: valid
    float4 x1 = vp[tid + 256];               //            max 511
    float4 x2 = vp[tid + 512];               //            max 767
    float4 x3 = vp[tid + 768];               //            max 1023
    float4 x4 = vp[tid + 1024];              //            max 1279
    float4 x5 = vp[tid + 1280];              //            max 1535  < 1655: valid
    float4 x6 = vp[v6ok ? li6 : 0];          //            max 1791: clamp + mask

    // ---- consume ------------------------------------------------------------
    float s0 = 0.0f, s1 = 0.0f, s2 = 0.0f, s3 = 0.0f;
    float v1 = FNEG, v2 = FNEG;
    int   i1 = 0x7fffffff, i2 = 0x7fffffff;

    auto top2 = [&](float x, int c) {        // branchless: 2 cmp + 4 cndmask
        bool g1 = (x > v1);
        bool g2 = (x > v2);
        v2 = g1 ? v1 : (g2 ? x : v2);
        i2 = g1 ? i1 : (g2 ? c : i2);
        v1 = g1 ? x : v1;
        i1 = g1 ? c : i1;
    };
    auto proc4 = [&](float4 x, int c) {
        s0 += __expf(x.x - PIVOT);
        s1 += __expf(x.y - PIVOT);
        s2 += __expf(x.z - PIVOT);
        s3 += __expf(x.w - PIVOT);
        top2((c == 0) ? FNEG : x.x, c);      // blank col 0 excluded from top2
        top2(x.y, c + 1);
        top2(x.z, c + 2);
        top2(x.w, c + 3);
    };

    proc4(x0, h + (tid << 2));
    proc4(x1, h + ((tid + 256) << 2));
    proc4(x2, h + ((tid + 512) << 2));
    proc4(x3, h + ((tid + 768) << 2));
    proc4(x4, h + ((tid + 1024) << 2));
    proc4(x5, h + ((tid + 1280) << 2));
    if (!v6ok) { x6.x = FNEG; x6.y = FNEG; x6.z = FNEG; x6.w = FNEG; }  // exp->0, top2 never
    proc4(x6, h + (li6 << 2));

    // boundaries: head (cols 0..h-1; col 0 excluded from top2) and tail
    s0 += __expf(headx - PIVOT);             // FNEG -> 0 when masked
    top2((tid == 0) ? FNEG : headx, tid);
    s0 += __expf(tailx - PIVOT);
    top2(tailx, t0 + tid);

    // ---- wave butterfly reduce ----------------------------------------------
    float s = (s0 + s1) + (s2 + s3);
    for (int off = 32; off > 0; off >>= 1) {
        s += __shfl_xor(s, off);
        float w1 = __shfl_xor(v1, off); int j1 = __shfl_xor(i1, off);
        float w2 = __shfl_xor(v2, off); int j2 = __shfl_xor(i2, off);
        bool b1 = (w1 > v1) || (w1 == v1 && j1 < i1);
        bool b2a = (v1 > w2) || (v1 == w2 && i1 < j2);
        bool b2b = (w1 > v2) || (w1 == v2 && j1 < i2);
        float nv2 = b1 ? (b2a ? v1 : w2) : (b2b ? w1 : v2);
        int   ni2 = b1 ? (b2a ? i1 : j2) : (b2b ? j1 : i2);
        v1 = b1 ? w1 : v1; i1 = b1 ? j1 : i1;
        v2 = nv2; i2 = ni2;
    }

    // ---- cross-wave (4 waves) via LDS ---------------------------------------
    __shared__ float ss_[4], sv1[4], sv2[4];
    __shared__ int   si1[4], si2[4];
    int wave = tid >> 6, lane = tid & 63;
    if (lane == 0) { ss_[wave] = s; sv1[wave] = v1; si1[wave] = i1; sv2[wave] = v2; si2[wave] = i2; }
    __syncthreads();
    if (tid == 0) {
        for (int w = 1; w < 4; ++w) {
            s += ss_[w];
            float w1 = sv1[w]; int j1 = si1[w]; float w2 = sv2[w]; int j2 = si2[w];
            bool b1 = (w1 > v1) || (w1 == v1 && j1 < i1);
            if (b1) {
                bool b2 = (v1 > w2) || (v1 == w2 && i1 < j2);
                v2 = b2 ? v1 : w2; i2 = b2 ? i1 : j2;
                v1 = w1; i1 = j1;
            } else {
                bool b2 = (w1 > v2) || (w1 == v2 && j1 < i2);
                if (b2) { v2 = w1; i2 = j1; }
            }
        }
        int b = r >> 6, t = r & 63;          // TT = 64
        int tr = t * BB + b;                 // [T][B] transposed
        lse_t[tr] = PIVOT + __logf(s);
        t1v[tr] = v1; t1i[tr] = i1;
        t2v[tr] = v2; t2i[tr] = i2;
    }
}

// ---------------------------------------------------------------------------
// Kernel 2: merged CTC + beam. Both run SHIFT-INVARIANT (raw preds, no
// per-frame lse subtraction); a single sum(lse) correction is applied at the
// end — every trellis/beam path accumulates exactly one emission per frame.
// ---------------------------------------------------------------------------
__global__ __launch_bounds__(256) void ctc_beam_k(
    const float* __restrict__ preds, const float* __restrict__ lse_t,
    const float* __restrict__ t1v, const float* __restrict__ t2v,
    const int* __restrict__ t1i, const int* __restrict__ t2i,
    const int* __restrict__ text, const int* __restrict__ length,
    const int* __restrict__ preds_size,
    const int* __restrict__ smooth_text, const int* __restrict__ smooth_length,
    float* __restrict__ nllm, float* __restrict__ cal, float* __restrict__ ranking)
{
    if (blockIdx.x == CTC_BLOCKS) {
        // ---------------- beam search (confidence), one thread per sample ----
        int b = threadIdx.x;
        if (b >= BB) return;
        const float* pb = preds + (size_t)b * TT * CC;

        float sum_lse = 0.0f;                      // not in the dependent chain
        #pragma unroll 8
        for (int t = 0; t < TT; ++t) sum_lse += lse_t[t * BB + b];

        float lpb = 0.0f, lpnb = NEG;
        int last = -1;
        float pf0[8];
        #pragma unroll
        for (int i = 0; i < 8; ++i) pf0[i] = pb[(size_t)i * CC];   // blank column
        float lplast_raw = 0.0f;
        for (int t = 0; t < TT; ++t) {
            int tr = t * BB + b;
            float w1 = t1v[tr]; int j1 = t1i[tr];
            float w2 = t2v[tr]; int j2 = t2i[tr];
            float lp0 = pf0[t & 7];
            if (t + 8 < TT) pf0[t & 7] = pb[(size_t)(t + 8) * CC];
            float tot = lae(lpb, lpnb);
            float new_pb = tot + lp0;
            float rep = (last >= 0) ? (lpnb + lplast_raw) : NEG;
            float keep = lae(new_pb, rep);
            float best_ext; int best_c;
            if (j1 == last) {
                float eA = lpb + w1;               // ext[last] uses lpb base
                float eB = tot + w2;               // runner-up with tot base
                if (eA > eB || (eA == eB && last < j2)) { best_ext = eA; best_c = last; }
                else                                    { best_ext = eB; best_c = j2; }
            } else {
                best_ext = tot + w1;               // tot>=lpb and w1>=raw[last]
                best_c = j1;
            }
            bool take = best_ext > keep;
            lpb  = take ? NEG : new_pb;
            lpnb = take ? best_ext : rep;
            last = take ? best_c : last;
            if (t + 1 < TT && last >= 0) lplast_raw = pb[(size_t)(t + 1) * CC + last];
        }
        float score = lae(lpb, lpnb) - sum_lse;
        float conf = __expf(score * (1.0f / TT));
        float om = 1.0f - conf;
        ranking[b] = 0.01f + 0.99f * om * om;   // SMOOTH_TAIL + (1-SMOOTH_TAIL)(1-conf)^2
        return;
    }

    // ---------------- CTC alpha recursion: one wave per target ---------------
    int wave = threadIdx.x >> 6, lane = threadIdx.x & 63;
    int n = blockIdx.x * 4 + wave;
    if (n >= NCTC) return;
    bool master = n < BB;
    int b, tlen, input_len;
    const int* tgt;
    if (master) {
        b = n; tgt = text + (size_t)n * LL; tlen = length[n]; input_len = preds_size[b];
    } else {
        int ns = n - BB;
        b = ns / KK; tgt = smooth_text + (size_t)ns * LSS; tlen = smooth_length[ns]; input_len = TT;
    }

    // extended label per lane (state s = lane): even -> blank(0), odd -> tgt[(s-1)/2]
    int s = lane;
    int ext = 0; bool skipok = false;
    if (s < SS && (s & 1)) {
        int li = (s - 1) >> 1;
        ext = tgt[li];
        skipok = (ext != 0) && (li == 0 || ext != tgt[li - 1]);
    }

    const float* pb = preds + (size_t)b * TT * CC;

    // sum of lse over t < input_len (lane = t), wave-reduced once
    float sum_lse = (lane < input_len) ? lse_t[lane * BB + b] : 0.0f;
    for (int off = 32; off > 0; off >>= 1) sum_lse += __shfl_xor(sum_lse, off);

    float alpha = NEG;
    if (s < 2) alpha = pb[ext];              // raw init (t=0)

    // 8-deep gather prefetch: addresses lane-constant (ext fixed per lane)
    float pf[8];
    #pragma unroll
    for (int i = 0; i < 8; ++i) pf[i] = pb[(size_t)(1 + i) * CC + ext];
    for (int t = 1; t < TT; ++t) {
        int slot = (t - 1) & 7;
        float lp = pf[slot];                 // raw emission
        if (t + 8 < TT) pf[slot] = pb[(size_t)(t + 8) * CC + ext];
        float a0 = alpha;
        float a1 = __shfl_up(alpha, 1); a1 = (lane >= 1) ? a1 : NEG;
        float a2 = __shfl_up(alpha, 2); a2 = (lane >= 2 && skipok) ? a2 : NEG;
        float m = fmaxf(a0, fmaxf(a1, a2));
        float tot = m + __logf(__expf(a0 - m) + __expf(a1 - m) + __expf(a2 - m));
        float anew = tot + lp;
        alpha = (t < input_len) ? anew : alpha;
    }

    int il = 2 * tlen;                        // <= 50 < SS
    float a_bl = __shfl(alpha, il);
    float a_ch = __shfl(alpha, il > 0 ? il - 1 : 0);
    float nll = sum_lse - lae(a_bl, a_ch);    // normalization applied once
    if (nll > 1e29f) nll = 0.0f;              // zero_infinity
    if (lane == 0) {
        float v = nll / (float)tlen;
        if (master) nllm[b] = v;
        else        atomicAdd(&cal[b], v * (1.0f / KK));
    }
}

// ---------------------------------------------------------------------------
// Kernel 3: final scalar: mean_b( nllm[b] + ALPHA * ranking[b] * cal[b] )
// ---------------------------------------------------------------------------
__global__ __launch_bounds__(128) void final_k(
    const float* __restrict__ nllm, const float* __restrict__ ranking,
    const float* __restrict__ cal, float* __restrict__ out)
{
    int b = threadIdx.x;
    float v = nllm[b] + 0.1f * ranking[b] * cal[b];
    for (int off = 32; off > 0; off >>= 1) v += __shfl_xor(v, off);
    __shared__ float sv[2];
    if ((b & 63) == 0) sv[b >> 6] = v;
    __syncthreads();
    if (b == 0) out[0] = (sv[0] + sv[1]) * (1.0f / BB);
}

extern "C" void kernel_launch(void* const* d_in, const int* in_sizes, int n_in,
                              void* d_out, int out_size, void* d_ws, size_t ws_size,
                              hipStream_t stream)
{
    const float* preds         = (const float*)d_in[0];
    const int*   text          = (const int*)d_in[1];
    const int*   preds_size    = (const int*)d_in[2];
    const int*   length        = (const int*)d_in[3];
    const int*   smooth_text   = (const int*)d_in[4];
    const int*   smooth_length = (const int*)d_in[5];
    float* out = (float*)d_out;

    // workspace layout (floats): lse_t | t1v | t2v | t1i | t2i | ranking | nllm | cal
    const int RT = BB * TT;  // 8192 rows
    float* ws     = (float*)d_ws;
    float* lse_t  = ws;
    float* t1v    = ws + RT;
    float* t2v    = ws + 2 * RT;
    int*   t1i    = (int*)(ws + 3 * RT);
    int*   t2i    = (int*)(ws + 4 * RT);
    float* ranking = ws + 5 * RT;
    float* nllm    = ranking + BB;
    float* cal     = nllm + BB;

    row_stats_k<<<RT, 256, 0, stream>>>(preds, lse_t, t1v, t2v, t1i, t2i, cal);
    ctc_beam_k<<<CTC_BLOCKS + 1, 256, 0, stream>>>(preds, lse_t, t1v, t2v, t1i, t2i,
                                                   text, length, preds_size,
                                                   smooth_text, smooth_length,
                                                   nllm, cal, ranking);
    final_k<<<1, 128, 0, stream>>>(nllm, ranking, cal, out);
}